// Round 1
// 163.268 us; speedup vs baseline: 1.0009x; 1.0009x over previous
//
#include <hip/hip_runtime.h>

// NeuSSampler PDF importance resampling — segment-parallel scan + LDS payload
// scatter + output-parallel coalesced epilogue.
//
// One wave per ray, 4 waves/block. Lane l owns weights/bins pair (2l, 2l+1).
// Wave-wide inclusive scan of pair sums via the classic gfx9 DPP sequence
// (row_shr:1/2/4/8 + row_bcast:15 rmask 0xa + row_bcast:31 rmask 0xc).
//
// v2 restructure: the divergent per-segment loops no longer compute the
// interpolation + scattered global stores (that was ~8 inst/trip under
// wave-max serialization). Instead each nonempty segment scatters ONE
// loop-invariant 16B payload {c_start, rcp(c_end-c_start),
// fmaf(b_start,fmn,near), (b_end-b_start)*fmn} into a per-wave LDS slot
// array (ds_write_b128 + addr inc = 2 inst/trip). A uniform second pass has
// lane j read slot j, interp, and issue one coalesced 256B row store
// (output 64 handled by lane 0 under mask). Segment ranges tile [0,65)
// exactly (shared cdf edges are bit-identical across lanes), so every slot
// is written exactly once. LDS slice is wave-private -> no s_barrier, just
// lgkmcnt(0).
//
// Degenerate cases unchanged vs v1: duplicate cdf entries -> empty segment
// (no slots); d==0 with nonempty range -> rcp(0)=inf -> t=+/-inf or NaN ->
// fmaxf(NaN,0)=0 / fminf(inf,1)=1, matching the reference's
// nan_to_num + clip gather semantics.

#define DPP_FADD(x, ctrl, rmask)                                             \
    ((x) + __int_as_float(__builtin_amdgcn_update_dpp(                       \
               0, __float_as_int(x), (ctrl), (rmask), 0xf, true)))

__global__ __launch_bounds__(256) void neus_sampler_kernel(
    const float* __restrict__ weights,
    const float* __restrict__ bins_g,
    const float* __restrict__ nears,
    const float* __restrict__ fars,
    float* __restrict__ out,
    int R)
{
    constexpr int S  = 128;   // weights per ray
    constexpr int NB = 65;    // output samples per ray
    constexpr float HPAD = 1e-5f;

    __shared__ float4 pay[4][NB];               // 4160 B/block, wave-private rows

    const int lane = threadIdx.x & 63;
    const int wv   = threadIdx.x >> 6;
    const int ray  = blockIdx.x * 4 + wv;
    if (ray >= R) return;                       // wave-uniform (no barriers)
    const int uray = __builtin_amdgcn_readfirstlane(ray);  // SGPR base addrs

    // ---- coalesced vector loads: 2 weights + 2 bin edges per lane ----
    const float2 wpair =
        reinterpret_cast<const float2*>(weights + (size_t)uray * S)[lane];
    const float* brow = bins_g + (size_t)uray * (S + 1);
    const float2 bpair = reinterpret_cast<const float2*>(brow)[lane];
    const float b_last = brow[S];               // uniform -> s_load

    const float w1 = wpair.y + HPAD;
    float ps = (wpair.x + HPAD) + w1;           // pair sum

    // ---- wave64 inclusive scan (DPP): ps = cumsum(w)[2l+1] ----
    ps = DPP_FADD(ps, 0x111, 0xf);  // row_shr:1
    ps = DPP_FADD(ps, 0x112, 0xf);  // row_shr:2
    ps = DPP_FADD(ps, 0x114, 0xf);  // row_shr:4
    ps = DPP_FADD(ps, 0x118, 0xf);  // row_shr:8
    ps = DPP_FADD(ps, 0x142, 0xa);  // row_bcast:15 -> rows 1,3
    ps = DPP_FADD(ps, 0x143, 0xc);  // row_bcast:31 -> rows 2,3

    const float total =
        __int_as_float(__builtin_amdgcn_readlane(__float_as_int(ps), 63));
    const float padding = fmaxf(1e-5f - total, 0.0f);   // relu(EPS - w_sum)
    const float padc    = padding * (1.0f / S);
    const float inv     = __builtin_amdgcn_rcpf(total + padding);

    // ---- per-lane cdf edges (registers only) ----
    const float c_hi  = fminf(1.0f, fmaf((float)(2 * lane + 2), padc, ps) * inv);
    const float c_mid = fminf(1.0f, fmaf((float)(2 * lane + 1), padc, ps - w1) * inv);
    float c_lo = __shfl_up(c_hi, 1, 64);
    if (lane == 0) c_lo = 0.0f;                 // cdf[0]
    float b2 = __shfl_down(bpair.x, 1, 64);     // bins[2l+2]
    if (lane == 63) b2 = b_last;                // bins[128]

    const float nearv = nears[uray];            // uniform -> s_load
    const float farv  = fars[uray];
    const float fmn   = farv - nearv;

    // first query index j with u_j >= c  (u_j = (2j+1)/130)
    auto jf = [](float c) -> int {
        int j = (int)ceilf(fmaf(65.0f, c, -0.5f));
        return j < 0 ? 0 : (j > NB ? NB : j);
    };

    const int j0 = jf(c_lo);
    const int j2 = (lane == 63) ? NB : jf(c_hi);   // last segment: open top
    int j1 = jf(c_mid);
    j1 = j1 < j0 ? j0 : (j1 > j2 ? j2 : j1);       // tile [j0,j2) exactly

    float4* const wp = &pay[wv][0];

    // segment k=2l: queries [j0,j1), edges [c_lo,c_mid), bins [bpair.x,bpair.y]
    if (j1 > j0) {
        const float r = __builtin_amdgcn_rcpf(c_mid - c_lo);
        const float4 v = make_float4(c_lo, r,
                                     fmaf(bpair.x, fmn, nearv),
                                     (bpair.y - bpair.x) * fmn);
        for (int j = j0; j < j1; ++j) wp[j] = v;   // ds_write_b128, invariant v
    }
    // segment k=2l+1: queries [j1,j2), edges [c_mid,c_hi), bins [bpair.y,b2]
    if (j2 > j1) {
        const float r = __builtin_amdgcn_rcpf(c_hi - c_mid);  // inf if d==0
        const float4 v = make_float4(c_mid, r,
                                     fmaf(bpair.y, fmn, nearv),
                                     (b2 - bpair.y) * fmn);
        for (int j = j1; j < j2; ++j) wp[j] = v;
    }

    // same-wave scatter -> gather: DS ops return in order; drain them.
    asm volatile("s_waitcnt lgkmcnt(0)" ::: "memory");

    // ---- uniform epilogue: lane j computes output j, coalesced store ----
    float* const orow = out + (size_t)uray * NB;
    {
        const float4 p  = wp[lane];
        const float  u  = (float)(2 * lane + 1) * (1.0f / 130.0f);
        const float  t  = (u - p.x) * p.y;
        const float  tc = fminf(fmaxf(t, 0.0f), 1.0f);  // NaN-safe: ->0
        orow[lane] = fmaf(tc, p.w, p.z);
    }
    if (lane == 0) {                                    // output 64
        const float4 p  = wp[64];
        const float  t  = (129.0f / 130.0f - p.x) * p.y;
        const float  tc = fminf(fmaxf(t, 0.0f), 1.0f);
        orow[64] = fmaf(tc, p.w, p.z);
    }
}

extern "C" void kernel_launch(void* const* d_in, const int* in_sizes, int n_in,
                              void* d_out, int out_size, void* d_ws, size_t ws_size,
                              hipStream_t stream) {
    const float* weights = (const float*)d_in[0];   // [R,128,1]
    const float* ebins   = (const float*)d_in[1];   // [R,129]
    const float* nears   = (const float*)d_in[2];   // [R,1]
    const float* fars    = (const float*)d_in[3];   // [R,1]
    float* out = (float*)d_out;                     // [R,65]
    const int R = in_sizes[0] / 128;
    const int blocks = (R + 3) / 4;                 // 4 rays (waves) per block
    hipLaunchKernelGGL(neus_sampler_kernel, dim3(blocks), dim3(256), 0, stream,
                       weights, ebins, nears, fars, out, R);
}